// Round 7
// baseline (2702.477 us; speedup 1.0000x reference)
//
#include <hip/hip_runtime.h>

typedef short bf16x8 __attribute__((ext_vector_type(8)));
typedef float f32x4  __attribute__((ext_vector_type(4)));

#define TSTEPS 1000
#define BATCH  512
#define HID    64
#define INPD   64
#define FEAT   128
#define KEEP   5
#define KH     320
#define ALPHA  0.2f
#define BB     2
#define NBLK   (BATCH/BB)   // 256
#define NTHR   512

#define MFMA(a,b,c) __builtin_amdgcn_mfma_f32_16x16x32_bf16(a, b, c, 0, 0, 0)

template<int P> struct IC { static constexpr int v = P; };

// split 4 f32 into bf16-hi (truncated) and bf16-lo (rounded residual), packed 2-per-u32
__device__ __forceinline__ void pack4(float x0, float x1, float x2, float x3,
                                      unsigned &h0, unsigned &h1,
                                      unsigned &l0, unsigned &l1) {
  unsigned a0 = __float_as_uint(x0), a1 = __float_as_uint(x1);
  unsigned a2 = __float_as_uint(x2), a3 = __float_as_uint(x3);
  h0 = __builtin_amdgcn_perm(a1, a0, 0x07060302u);   // {bf16(x1), bf16(x0)}
  h1 = __builtin_amdgcn_perm(a3, a2, 0x07060302u);
  float r0 = x0 - __uint_as_float(a0 & 0xFFFF0000u);
  float r1 = x1 - __uint_as_float(a1 & 0xFFFF0000u);
  float r2 = x2 - __uint_as_float(a2 & 0xFFFF0000u);
  float r3 = x3 - __uint_as_float(a3 & 0xFFFF0000u);
  asm("v_cvt_pk_bf16_f32 %0, %1, %2" : "=v"(l0) : "v"(r0), "v"(r1));
  asm("v_cvt_pk_bf16_f32 %0, %1, %2" : "=v"(l1) : "v"(r2), "v"(r3));
}

__device__ __forceinline__ void pack_frag(float4 v0, float4 v1, bf16x8 &hi, bf16x8 &lo) {
  int4 h4, l4;
  pack4(v0.x, v0.y, v0.z, v0.w, (unsigned&)h4.x, (unsigned&)h4.y, (unsigned&)l4.x, (unsigned&)l4.y);
  pack4(v1.x, v1.y, v1.z, v1.w, (unsigned&)h4.z, (unsigned&)h4.w, (unsigned&)l4.z, (unsigned&)l4.w);
  hi = __builtin_bit_cast(bf16x8, h4);
  lo = __builtin_bit_cast(bf16x8, l4);
}

__device__ __forceinline__ void load_wfrag(const float* p, bf16x8 &hi, bf16x8 &lo) {
  float4 v0 = *(const float4*)p;
  float4 v1 = *(const float4*)(p + 4);
  pack_frag(v0, v1, hi, lo);
}

// ---------------- single persistent MFMA kernel, 2 barriers/step ----------------
// 256 blocks (1/CU) x 8 waves, BB=2.
// P1 (all): MLP1 30 MFMA -> a_s ; w4-7 issue raw x[t+2] loads.   bar A
// P2: w0-3: RNN 6 + MLP2 full-K 12, finalize h_t, io write, stage B1lds
//     w4-7: pack x[t+1] (loads issued a full step ago), XIN 6 -> xin_s[(t+1)&1]
//                                                                 bar B
__global__ __launch_bounds__(NTHR, 2) void seq_kernel(
    const float* __restrict__ x,    float* __restrict__ io,
    const float* __restrict__ h0g,
    const float* __restrict__ W_in, const float* __restrict__ b_in,
    const float* __restrict__ W_hh, const float* __restrict__ b_hh,
    const float* __restrict__ W1,   const float* __restrict__ b1,
    const float* __restrict__ W2,   const float* __restrict__ b2) {

  __shared__ __align__(16) short B1lds[2048];   // newest-h frag staging
  __shared__ __align__(16) short a_s[544];      // relu(mlp1) bf16, col stride 264
  __shared__ __align__(16) float xin_s[2][128]; // xin incl biases [par][col2*64+h]

  const int tid  = threadIdx.x;
  const int w    = tid >> 6;
  const int lane = tid & 63;
  const int q15  = lane & 15;
  const int g    = lane >> 4;
  const int b0   = blockIdx.x * BB;
  const bool gA  = (w < 4);
  const int r0c  = 16*(w & 3) + 4*g;   // 64-row base (RNN / MLP2 / h / xin)
  const int f0   = 16*w + 4*g;         // 128-row base (MLP1)
  const int c01  = q15 & 1;

  const int aW  = q15*264 + f0;        // a_s write (hi), +128 lo; q15<2 only
  const int aRb = c01*264 + 8*g;       // a_s read base (+kt*32, +128 lo)
  const int bWH = (r0c>>5)*1024 + ((r0c>>3)&3)*128 + q15*8 + (r0c&7);
  const int bRD = g*128 + q15*8;

  const f32x4 vz = {0.f, 0.f, 0.f, 0.f};

  // ---- weight fragments ----
  bf16x8 w1h[10], w1l[10];
#pragma unroll
  for (int jt = 0; jt < 10; ++jt)
    load_wfrag(W1 + (size_t)(16*w + q15)*KH + jt*32 + 8*g, w1h[jt], w1l[jt]);

  f32x4 b1r = *(const f32x4*)(b1 + f0);
  bf16x8 whh_h[2], whh_l[2];   // w0-3
  bf16x8 w2h[4],  w2l[4];      // w0-3: W2 rows 16w, full K
  bf16x8 winh[2], winl[2];     // w4-7
  f32x4 biasv = vz, b2r = vz;
  if (gA) {
#pragma unroll
    for (int kt = 0; kt < 2; ++kt)
      load_wfrag(W_hh + (size_t)(16*w + q15)*HID + kt*32 + 8*g, whh_h[kt], whh_l[kt]);
#pragma unroll
    for (int kt = 0; kt < 4; ++kt)
      load_wfrag(W2 + (size_t)(16*w + q15)*FEAT + kt*32 + 8*g, w2h[kt], w2l[kt]);
    b2r = *(const f32x4*)(b2 + r0c);
  } else {
#pragma unroll
    for (int kt = 0; kt < 2; ++kt)
      load_wfrag(W_in + (size_t)(16*(w-4) + q15)*INPD + kt*32 + 8*g, winh[kt], winl[kt]);
    biasv = *(const f32x4*)(b_in + r0c) + *(const f32x4*)(b_hh + r0c);
  }

  for (int i = tid; i < 1024; i += NTHR) ((unsigned*)B1lds)[i] = 0u;
  __syncthreads();

  // ---- state init ----
  f32x4 hprev = vz;
  float4 xc0, xc1, xc2, xc3;            // raw x[t+1] (w4-7)
  if (gA) {
    if (q15 < 2) {
      hprev = *(const f32x4*)(h0g + (size_t)(b0 + q15)*HID + r0c);
      unsigned n0, n1, n2, n3;
      pack4(hprev.x, hprev.y, hprev.z, hprev.w, n0, n1, n2, n3);
      *(uint2*)&B1lds[bWH]       = make_uint2(n0, n1);
      *(uint2*)&B1lds[bWH + 512] = make_uint2(n2, n3);
    }
  } else {
    // xin for t=0
    const float* xp = x + (size_t)(b0 + c01)*INPD + 8*g;
    float4 v0 = *(const float4*)xp;        float4 v1 = *(const float4*)(xp + 4);
    float4 v2 = *(const float4*)(xp + 32); float4 v3 = *(const float4*)(xp + 36);
    bf16x8 th0, tl0, th1, tl1;
    pack_frag(v0, v1, th0, tl0);
    pack_frag(v2, v3, th1, tl1);
    f32x4 dhh = biasv, dhl = vz, dlh = vz;
    dhh = MFMA(winh[0], th0, dhh); dhh = MFMA(winh[1], th1, dhh);
    dhl = MFMA(winh[0], tl0, dhl); dhl = MFMA(winh[1], tl1, dhl);
    dlh = MFMA(winl[0], th0, dlh); dlh = MFMA(winl[1], th1, dlh);
    f32x4 xi = (dhh + dhl) + dlh;
    if (q15 < 2) *(f32x4*)&xin_s[0][q15*64 + r0c] = xi;
    // issue raw x[1] (consumed in P2 of t=0)
    const float* xq = x + (size_t)1*BATCH*INPD + (size_t)(b0 + c01)*INPD + 8*g;
    xc0 = *(const float4*)xq;        xc1 = *(const float4*)(xq + 4);
    xc2 = *(const float4*)(xq + 32); xc3 = *(const float4*)(xq + 36);
  }

  bf16x8 rbh[KEEP][2], rbl[KEEP][2];
  const bf16x8 z8 = {0,0,0,0,0,0,0,0};
#pragma unroll
  for (int s = 0; s < KEEP; ++s) {
    rbh[s][0] = z8; rbl[s][0] = z8; rbh[s][1] = z8; rbl[s][1] = z8;
  }
  __syncthreads();

  int t5 = 0;
  auto step = [&](auto pc) {
    constexpr int ph = decltype(pc)::v;
    constexpr int sN = (ph + 4) % 5;           // slot of h_{t-1}
    const int t = t5 + ph;

    // ---- P1 ----
    float4 xn0, xn1, xn2, xn3;                 // w4-7: raw x[t+2]
    if (!gA) {
      int tn = t + 2; if (tn > TSTEPS-1) tn = TSTEPS-1;
      const float* xp = x + (size_t)tn*BATCH*INPD + (size_t)(b0 + c01)*INPD + 8*g;
      xn0 = *(const float4*)xp;        xn1 = *(const float4*)(xp + 4);
      xn2 = *(const float4*)(xp + 32); xn3 = *(const float4*)(xp + 36);
    }

    rbh[sN][0] = *(const bf16x8*)&B1lds[bRD];
    rbl[sN][0] = *(const bf16x8*)&B1lds[bRD + 512];
    rbh[sN][1] = *(const bf16x8*)&B1lds[bRD + 1024];
    rbl[sN][1] = *(const bf16x8*)&B1lds[bRD + 1536];

    // MLP1: K=320, 5 slots x 2 ktiles, 3-product split; newest slot last
    f32x4 chh = vz, chl = vz, clh = vz;
#pragma unroll
    for (int e = 1; e <= 5; ++e) {
      const int s = (sN + e) % 5;
      const int r = ((s - ph) % 5 + 5) % 5;
#pragma unroll
      for (int q = 0; q < 2; ++q) {
        const int jt = 2*r + q;
        chh = MFMA(w1h[jt], rbh[s][q], chh);
        chl = MFMA(w1h[jt], rbl[s][q], chl);
        clh = MFMA(w1l[jt], rbh[s][q], clh);
      }
    }
    {
      f32x4 apre = (chh + chl) + (clh + b1r);
      f32x4 av = __builtin_elementwise_max(apre, vz);
      unsigned p0, p1, p2, p3;
      pack4(av.x, av.y, av.z, av.w, p0, p1, p2, p3);
      if (q15 < 2) {
        *(uint2*)&a_s[aW]       = make_uint2(p0, p1);
        *(uint2*)&a_s[aW + 128] = make_uint2(p2, p3);
      }
    }
    __syncthreads();   // bar A: a_s ready

    // ---- P2 ----
    if (gA) {
      bf16x8 ah0 = *(const bf16x8*)&a_s[aRb +   0];
      bf16x8 ah1 = *(const bf16x8*)&a_s[aRb +  32];
      bf16x8 ah2 = *(const bf16x8*)&a_s[aRb +  64];
      bf16x8 ah3 = *(const bf16x8*)&a_s[aRb +  96];
      bf16x8 al0 = *(const bf16x8*)&a_s[aRb + 128];
      bf16x8 al1 = *(const bf16x8*)&a_s[aRb + 160];
      bf16x8 al2 = *(const bf16x8*)&a_s[aRb + 192];
      bf16x8 al3 = *(const bf16x8*)&a_s[aRb + 224];
      f32x4 xinv = vz;
      if (q15 < 2) xinv = *(const f32x4*)&xin_s[t & 1][q15*64 + r0c];
      // RNN on newest frag (register operands, overlap a_s latency)
      f32x4 dhh = vz, dhl = vz, dlh = vz;
      dhh = MFMA(whh_h[0], rbh[sN][0], dhh); dhh = MFMA(whh_h[1], rbh[sN][1], dhh);
      dhl = MFMA(whh_h[0], rbl[sN][0], dhl); dhl = MFMA(whh_h[1], rbl[sN][1], dhl);
      dlh = MFMA(whh_l[0], rbh[sN][0], dlh); dlh = MFMA(whh_l[1], rbh[sN][1], dlh);
      // MLP2 full K
      f32x4 mhh = b2r, mhl = vz, mlh = vz;
      mhh = MFMA(w2h[0], ah0, mhh); mhl = MFMA(w2h[0], al0, mhl); mlh = MFMA(w2l[0], ah0, mlh);
      mhh = MFMA(w2h[1], ah1, mhh); mhl = MFMA(w2h[1], al1, mhl); mlh = MFMA(w2l[1], ah1, mlh);
      mhh = MFMA(w2h[2], ah2, mhh); mhl = MFMA(w2h[2], al2, mhl); mlh = MFMA(w2l[2], ah2, mlh);
      mhh = MFMA(w2h[3], ah3, mhh); mhl = MFMA(w2h[3], al3, mhl); mlh = MFMA(w2l[3], ah3, mlh);
      f32x4 pre = (dhh + dhl) + dlh + xinv;    // xin includes biases
      f32x4 rl = __builtin_elementwise_max(pre, vz);
      f32x4 hobs = hprev * (1.f - ALPHA) + rl * ALPHA;
      f32x4 hm = (mhh + mhl) + mlh;
      f32x4 hn = (t >= KEEP) ? (hobs + hm) * 0.5f : hobs;
      if (q15 < 2) {
        *(f32x4*)(io + (size_t)t*BATCH*HID + (size_t)(b0 + q15)*HID + r0c) = hn;
        if (t == TSTEPS-1)
          *(f32x4*)(io + (size_t)TSTEPS*BATCH*HID + (size_t)(b0 + q15)*HID + r0c) = hn;
        unsigned n0, n1, n2, n3;
        pack4(hn.x, hn.y, hn.z, hn.w, n0, n1, n2, n3);
        *(uint2*)&B1lds[bWH]       = make_uint2(n0, n1);
        *(uint2*)&B1lds[bWH + 512] = make_uint2(n2, n3);
      }
      hprev = hn;
    } else {
      bf16x8 th0, tl0, th1, tl1;
      pack_frag(xc0, xc1, th0, tl0);
      pack_frag(xc2, xc3, th1, tl1);
      f32x4 dhh = biasv, dhl = vz, dlh = vz;
      dhh = MFMA(winh[0], th0, dhh); dhh = MFMA(winh[1], th1, dhh);
      dhl = MFMA(winh[0], tl0, dhl); dhl = MFMA(winh[1], tl1, dhl);
      dlh = MFMA(winl[0], th0, dlh); dlh = MFMA(winl[1], th1, dlh);
      f32x4 xi = (dhh + dhl) + dlh;
      if (q15 < 2) *(f32x4*)&xin_s[(t + 1) & 1][q15*64 + r0c] = xi;
      xc0 = xn0; xc1 = xn1; xc2 = xn2; xc3 = xn3;
    }
    __syncthreads();   // bar B: B1lds + xin_s staged
  };

  for (t5 = 0; t5 < TSTEPS; t5 += 5) {
    step(IC<0>{});
    step(IC<1>{});
    step(IC<2>{});
    step(IC<3>{});
    step(IC<4>{});
  }
}

extern "C" void kernel_launch(void* const* d_in, const int* in_sizes, int n_in,
                              void* d_out, int out_size, void* d_ws, size_t ws_size,
                              hipStream_t stream) {
  (void)in_sizes; (void)n_in; (void)out_size; (void)d_ws; (void)ws_size;
  const float* x    = (const float*)d_in[0];
  const float* h0   = (const float*)d_in[1];
  const float* W_in = (const float*)d_in[2];
  const float* b_in = (const float*)d_in[3];
  const float* W_hh = (const float*)d_in[4];
  const float* b_hh = (const float*)d_in[5];
  const float* W1   = (const float*)d_in[6];
  const float* b1   = (const float*)d_in[7];
  const float* W2   = (const float*)d_in[8];
  const float* b2   = (const float*)d_in[9];
  float* out = (float*)d_out;

  seq_kernel<<<NBLK, NTHR, 0, stream>>>(x, out, h0, W_in, b_in, W_hh, b_hh, W1, b1, W2, b2);
}

// Round 8
// 2031.530 us; speedup vs baseline: 1.3303x; 1.3303x over previous
//
#include <hip/hip_runtime.h>

typedef short bf16x8 __attribute__((ext_vector_type(8)));
typedef float f32x4  __attribute__((ext_vector_type(4)));

#define TSTEPS 1000
#define BATCH  512
#define HID    64
#define INPD   64
#define FEAT   128
#define KEEP   5
#define KH     320
#define ALPHA  0.2f
#define BB     2
#define NBLK   (BATCH/BB)   // 256
#define NTHR   512

#define MFMA(a,b,c) __builtin_amdgcn_mfma_f32_16x16x32_bf16(a, b, c, 0, 0, 0)

template<int P> struct IC { static constexpr int v = P; };

// Raw barrier: flush own LDS writes, sync, fence. NO vmcnt drain (unlike
// __syncthreads) -> global loads/stores stay in flight across the barrier.
__device__ __forceinline__ void barrier_fast() {
  asm volatile("s_waitcnt lgkmcnt(0)" ::: "memory");
  __builtin_amdgcn_s_barrier();
  asm volatile("" ::: "memory");
}

// split 4 f32 into bf16-hi (truncated) and bf16-lo (rounded residual), packed 2-per-u32
__device__ __forceinline__ void pack4(float x0, float x1, float x2, float x3,
                                      unsigned &h0, unsigned &h1,
                                      unsigned &l0, unsigned &l1) {
  unsigned a0 = __float_as_uint(x0), a1 = __float_as_uint(x1);
  unsigned a2 = __float_as_uint(x2), a3 = __float_as_uint(x3);
  h0 = __builtin_amdgcn_perm(a1, a0, 0x07060302u);   // {bf16(x1), bf16(x0)}
  h1 = __builtin_amdgcn_perm(a3, a2, 0x07060302u);
  float r0 = x0 - __uint_as_float(a0 & 0xFFFF0000u);
  float r1 = x1 - __uint_as_float(a1 & 0xFFFF0000u);
  float r2 = x2 - __uint_as_float(a2 & 0xFFFF0000u);
  float r3 = x3 - __uint_as_float(a3 & 0xFFFF0000u);
  asm("v_cvt_pk_bf16_f32 %0, %1, %2" : "=v"(l0) : "v"(r0), "v"(r1));
  asm("v_cvt_pk_bf16_f32 %0, %1, %2" : "=v"(l1) : "v"(r2), "v"(r3));
}

__device__ __forceinline__ void pack_frag(float4 v0, float4 v1, bf16x8 &hi, bf16x8 &lo) {
  int4 h4, l4;
  pack4(v0.x, v0.y, v0.z, v0.w, (unsigned&)h4.x, (unsigned&)h4.y, (unsigned&)l4.x, (unsigned&)l4.y);
  pack4(v1.x, v1.y, v1.z, v1.w, (unsigned&)h4.z, (unsigned&)h4.w, (unsigned&)l4.z, (unsigned&)l4.w);
  hi = __builtin_bit_cast(bf16x8, h4);
  lo = __builtin_bit_cast(bf16x8, l4);
}

__device__ __forceinline__ void load_wfrag(const float* p, bf16x8 &hi, bf16x8 &lo) {
  float4 v0 = *(const float4*)p;
  float4 v1 = *(const float4*)(p + 4);
  pack_frag(v0, v1, hi, lo);
}

// ---------------- single persistent MFMA kernel (round-6 structure + raw barriers) ----------------
// 256 blocks (1/CU) x 8 waves, BB=2, 3 raw barriers/step, 42 MFMA per wave per step.
// P1 (all): MLP1 30 MFMA -> a_s         (w4-7 also issue raw x[t+2] loads at top)
// P2: w0-3: RNN 6 + MLP2-kt23 6 -> hobs,m2p (regs) | w4-7: MLP2-kt01 6 -> hm_s
// P3: w0-3: finalize h_t, io write, stage B1lds    | w4-7: pack x[t+1], XIN 6 -> xin_s
__global__ __launch_bounds__(NTHR, 2) void seq_kernel(
    const float* __restrict__ x,    float* __restrict__ io,
    const float* __restrict__ h0g,
    const float* __restrict__ W_in, const float* __restrict__ b_in,
    const float* __restrict__ W_hh, const float* __restrict__ b_hh,
    const float* __restrict__ W1,   const float* __restrict__ b1,
    const float* __restrict__ W2,   const float* __restrict__ b2) {

  __shared__ __align__(16) short B1lds[2048];   // newest-h frag staging
  __shared__ __align__(16) short a_s[544];      // relu(mlp1) bf16, col stride 264
  __shared__ __align__(16) float hm_s[128];     // mlp2 kt01 partial [col2][h64]
  __shared__ __align__(16) float xin_s[128];    // xin(t+1) incl biases [col2][h64]

  const int tid  = threadIdx.x;
  const int w    = tid >> 6;
  const int lane = tid & 63;
  const int q15  = lane & 15;
  const int g    = lane >> 4;
  const int b0   = blockIdx.x * BB;
  const bool gA  = (w < 4);
  const int r0c  = 16*(w & 3) + 4*g;   // 64-row base (RNN / MLP2 / h / xin)
  const int f0   = 16*w + 4*g;         // 128-row base (MLP1)
  const int c01  = q15 & 1;

  const int aW  = q15*264 + f0;        // a_s write (hi), +128 lo; q15<2 only
  const int aRb = c01*264 + 8*g;       // a_s read base (+kt*32, +128 lo)
  const int bWH = (r0c>>5)*1024 + ((r0c>>3)&3)*128 + q15*8 + (r0c&7);
  const int bRD = g*128 + q15*8;

  const f32x4 vz = {0.f, 0.f, 0.f, 0.f};

  // ---- weight fragments ----
  bf16x8 w1h[10], w1l[10];
#pragma unroll
  for (int jt = 0; jt < 10; ++jt)
    load_wfrag(W1 + (size_t)(16*w + q15)*KH + jt*32 + 8*g, w1h[jt], w1l[jt]);

  bf16x8 wxh[4], wxl[4];
  f32x4 biasv = vz, b2r = vz;
  f32x4 b1r = *(const f32x4*)(b1 + f0);
  if (gA) {
    // [0,1]=W_hh kt0,1 ; [2,3]=W2 rows 16w, kt2,3
#pragma unroll
    for (int kt = 0; kt < 2; ++kt) {
      load_wfrag(W_hh + (size_t)(16*w + q15)*HID  + kt*32 + 8*g,       wxh[kt],   wxl[kt]);
      load_wfrag(W2   + (size_t)(16*w + q15)*FEAT + (2+kt)*32 + 8*g,   wxh[2+kt], wxl[2+kt]);
    }
    b2r = *(const f32x4*)(b2 + r0c);
  } else {
    // [0,1]=W2 rows 16(w-4), kt0,1 ; [2,3]=W_in kt0,1
#pragma unroll
    for (int kt = 0; kt < 2; ++kt) {
      load_wfrag(W2   + (size_t)(16*(w-4) + q15)*FEAT + kt*32 + 8*g,   wxh[kt],   wxl[kt]);
      load_wfrag(W_in + (size_t)(16*(w-4) + q15)*INPD + kt*32 + 8*g,   wxh[2+kt], wxl[2+kt]);
    }
    biasv = *(const f32x4*)(b_in + r0c) + *(const f32x4*)(b_hh + r0c);
  }

  for (int i = tid; i < 1024; i += NTHR) ((unsigned*)B1lds)[i] = 0u;
  __syncthreads();

  // ---- state init ----
  f32x4 hprev = vz;
  float4 xc0, xc1, xc2, xc3;            // raw x[t+1] (w4-7)
  if (gA) {
    if (q15 < 2) {
      hprev = *(const f32x4*)(h0g + (size_t)(b0 + q15)*HID + r0c);
      unsigned n0, n1, n2, n3;
      pack4(hprev.x, hprev.y, hprev.z, hprev.w, n0, n1, n2, n3);
      *(uint2*)&B1lds[bWH]       = make_uint2(n0, n1);
      *(uint2*)&B1lds[bWH + 512] = make_uint2(n2, n3);
    }
  } else {
    // xin for t=0
    const float* xp = x + (size_t)(b0 + c01)*INPD + 8*g;
    float4 v0 = *(const float4*)xp;        float4 v1 = *(const float4*)(xp + 4);
    float4 v2 = *(const float4*)(xp + 32); float4 v3 = *(const float4*)(xp + 36);
    bf16x8 th0, tl0, th1, tl1;
    pack_frag(v0, v1, th0, tl0);
    pack_frag(v2, v3, th1, tl1);
    f32x4 dhh = biasv, dhl = vz, dlh = vz;
    dhh = MFMA(wxh[2], th0, dhh); dhh = MFMA(wxh[3], th1, dhh);
    dhl = MFMA(wxh[2], tl0, dhl); dhl = MFMA(wxh[3], tl1, dhl);
    dlh = MFMA(wxl[2], th0, dlh); dlh = MFMA(wxl[3], th1, dlh);
    f32x4 xi = (dhh + dhl) + dlh;
    if (q15 < 2) *(f32x4*)&xin_s[q15*64 + r0c] = xi;
    // issue raw x[1] (consumed in P3 of t=0)
    const float* xq = x + (size_t)1*BATCH*INPD + (size_t)(b0 + c01)*INPD + 8*g;
    xc0 = *(const float4*)xq;        xc1 = *(const float4*)(xq + 4);
    xc2 = *(const float4*)(xq + 32); xc3 = *(const float4*)(xq + 36);
  }

  bf16x8 rbh[KEEP][2], rbl[KEEP][2];
  const bf16x8 z8 = {0,0,0,0,0,0,0,0};
#pragma unroll
  for (int s = 0; s < KEEP; ++s) {
    rbh[s][0] = z8; rbl[s][0] = z8; rbh[s][1] = z8; rbl[s][1] = z8;
  }
  __syncthreads();

  int t5 = 0;
  auto step = [&](auto pc) {
    constexpr int ph = decltype(pc)::v;
    constexpr int sN = (ph + 4) % 5;           // slot of h_{t-1}
    const int t = t5 + ph;

    // ---- P1 ----
    float4 xn0, xn1, xn2, xn3;                 // w4-7: raw x[t+2], consumed next step P3
    if (!gA) {
      int tn = t + 2; if (tn > TSTEPS-1) tn = TSTEPS-1;
      const float* xp = x + (size_t)tn*BATCH*INPD + (size_t)(b0 + c01)*INPD + 8*g;
      xn0 = *(const float4*)xp;        xn1 = *(const float4*)(xp + 4);
      xn2 = *(const float4*)(xp + 32); xn3 = *(const float4*)(xp + 36);
    }

    rbh[sN][0] = *(const bf16x8*)&B1lds[bRD];
    rbl[sN][0] = *(const bf16x8*)&B1lds[bRD + 512];
    rbh[sN][1] = *(const bf16x8*)&B1lds[bRD + 1024];
    rbl[sN][1] = *(const bf16x8*)&B1lds[bRD + 1536];

    // MLP1: K=320, 5 slots x 2 ktiles, 3-product split; newest slot last
    f32x4 chh = vz, chl = vz, clh = vz;
#pragma unroll
    for (int e = 1; e <= 5; ++e) {
      const int s = (sN + e) % 5;
      const int r = ((s - ph) % 5 + 5) % 5;
#pragma unroll
      for (int q = 0; q < 2; ++q) {
        const int jt = 2*r + q;
        chh = MFMA(w1h[jt], rbh[s][q], chh);
        chl = MFMA(w1h[jt], rbl[s][q], chl);
        clh = MFMA(w1l[jt], rbh[s][q], clh);
      }
    }
    {
      f32x4 apre = (chh + chl) + (clh + b1r);
      f32x4 av = __builtin_elementwise_max(apre, vz);
      unsigned p0, p1, p2, p3;
      pack4(av.x, av.y, av.z, av.w, p0, p1, p2, p3);
      if (q15 < 2) {
        *(uint2*)&a_s[aW]       = make_uint2(p0, p1);
        *(uint2*)&a_s[aW + 128] = make_uint2(p2, p3);
      }
    }
    barrier_fast();   // bar A: a_s ready

    // ---- P2 ----
    f32x4 hobs = vz, m2p = vz;
    if (gA) {
      bf16x8 ah2 = *(const bf16x8*)&a_s[aRb +  64];
      bf16x8 ah3 = *(const bf16x8*)&a_s[aRb +  96];
      bf16x8 al2 = *(const bf16x8*)&a_s[aRb + 192];
      bf16x8 al3 = *(const bf16x8*)&a_s[aRb + 224];
      f32x4 xinv = vz;
      if (q15 < 2) xinv = *(const f32x4*)&xin_s[q15*64 + r0c];
      // RNN on newest frag (register operands, overlap a_s latency)
      f32x4 dhh = vz, dhl = vz, dlh = vz;
      dhh = MFMA(wxh[0], rbh[sN][0], dhh); dhh = MFMA(wxh[1], rbh[sN][1], dhh);
      dhl = MFMA(wxh[0], rbl[sN][0], dhl); dhl = MFMA(wxh[1], rbl[sN][1], dhl);
      dlh = MFMA(wxl[0], rbh[sN][0], dlh); dlh = MFMA(wxl[1], rbh[sN][1], dlh);
      // MLP2 kt2,3 partial (stays in registers)
      f32x4 mhh = vz, mhl = vz, mlh = vz;
      mhh = MFMA(wxh[2], ah2, mhh); mhh = MFMA(wxh[3], ah3, mhh);
      mhl = MFMA(wxh[2], al2, mhl); mhl = MFMA(wxh[3], al3, mhl);
      mlh = MFMA(wxl[2], ah2, mlh); mlh = MFMA(wxl[3], ah3, mlh);
      m2p = (mhh + mhl) + mlh;
      f32x4 pre = (dhh + dhl) + dlh + xinv;    // xin includes biases
      f32x4 rl = __builtin_elementwise_max(pre, vz);
      hobs = hprev * (1.f - ALPHA) + rl * ALPHA;
    } else {
      bf16x8 ah0 = *(const bf16x8*)&a_s[aRb +   0];
      bf16x8 ah1 = *(const bf16x8*)&a_s[aRb +  32];
      bf16x8 al0 = *(const bf16x8*)&a_s[aRb + 128];
      bf16x8 al1 = *(const bf16x8*)&a_s[aRb + 160];
      f32x4 mhh = vz, mhl = vz, mlh = vz;
      mhh = MFMA(wxh[0], ah0, mhh); mhh = MFMA(wxh[1], ah1, mhh);
      mhl = MFMA(wxh[0], al0, mhl); mhl = MFMA(wxh[1], al1, mhl);
      mlh = MFMA(wxl[0], ah0, mlh); mlh = MFMA(wxl[1], ah1, mlh);
      f32x4 hmv = (mhh + mhl) + mlh;
      if (q15 < 2) *(f32x4*)&hm_s[q15*64 + r0c] = hmv;
    }
    barrier_fast();   // bar B: hm_s ready

    // ---- P3 ----
    if (gA) {
      f32x4 hmo = vz;
      if (q15 < 2) hmo = *(const f32x4*)&hm_s[q15*64 + r0c];
      f32x4 hm = hmo + m2p + b2r;
      f32x4 hn = (t >= KEEP) ? (hobs + hm) * 0.5f : hobs;
      if (q15 < 2) {
        *(f32x4*)(io + (size_t)t*BATCH*HID + (size_t)(b0 + q15)*HID + r0c) = hn;
        if (t == TSTEPS-1)
          *(f32x4*)(io + (size_t)TSTEPS*BATCH*HID + (size_t)(b0 + q15)*HID + r0c) = hn;
        unsigned n0, n1, n2, n3;
        pack4(hn.x, hn.y, hn.z, hn.w, n0, n1, n2, n3);
        *(uint2*)&B1lds[bWH]       = make_uint2(n0, n1);
        *(uint2*)&B1lds[bWH + 512] = make_uint2(n2, n3);
      }
      hprev = hn;
    } else {
      bf16x8 th0, tl0, th1, tl1;
      pack_frag(xc0, xc1, th0, tl0);       // x[t+1], loaded a full step ago
      pack_frag(xc2, xc3, th1, tl1);
      f32x4 dhh = biasv, dhl = vz, dlh = vz;
      dhh = MFMA(wxh[2], th0, dhh); dhh = MFMA(wxh[3], th1, dhh);
      dhl = MFMA(wxh[2], tl0, dhl); dhl = MFMA(wxh[3], tl1, dhl);
      dlh = MFMA(wxl[2], th0, dlh); dlh = MFMA(wxl[3], th1, dlh);
      f32x4 xi = (dhh + dhl) + dlh;
      if (q15 < 2) *(f32x4*)&xin_s[q15*64 + r0c] = xi;
      xc0 = xn0; xc1 = xn1; xc2 = xn2; xc3 = xn3;
    }
    barrier_fast();   // bar C: B1lds + xin_s staged
  };

  for (t5 = 0; t5 < TSTEPS; t5 += 5) {
    step(IC<0>{});
    step(IC<1>{});
    step(IC<2>{});
    step(IC<3>{});
    step(IC<4>{});
  }
}

extern "C" void kernel_launch(void* const* d_in, const int* in_sizes, int n_in,
                              void* d_out, int out_size, void* d_ws, size_t ws_size,
                              hipStream_t stream) {
  (void)in_sizes; (void)n_in; (void)out_size; (void)d_ws; (void)ws_size;
  const float* x    = (const float*)d_in[0];
  const float* h0   = (const float*)d_in[1];
  const float* W_in = (const float*)d_in[2];
  const float* b_in = (const float*)d_in[3];
  const float* W_hh = (const float*)d_in[4];
  const float* b_hh = (const float*)d_in[5];
  const float* W1   = (const float*)d_in[6];
  const float* b1   = (const float*)d_in[7];
  const float* W2   = (const float*)d_in[8];
  const float* b2   = (const float*)d_in[9];
  float* out = (float*)d_out;

  seq_kernel<<<NBLK, NTHR, 0, stream>>>(x, out, h0, W_in, b_in, W_hh, b_hh, W1, b1, W2, b2);
}

// Round 9
// 1218.872 us; speedup vs baseline: 2.2172x; 1.6667x over previous
//
#include <hip/hip_runtime.h>

typedef short bf16x8 __attribute__((ext_vector_type(8)));
typedef float f32x4  __attribute__((ext_vector_type(4)));

#define TSTEPS 1000
#define BATCH  512
#define HID    64
#define INPD   64
#define FEAT   128
#define KEEP   5
#define KH     320
#define ALPHA  0.2f
#define BB     2
#define NBLK   (BATCH/BB)   // 256
#define NTHR   512

#define MFMA(a,b,c) __builtin_amdgcn_mfma_f32_16x16x32_bf16(a, b, c, 0, 0, 0)

template<int P> struct IC { static constexpr int v = P; };

// Raw barrier: flush own LDS writes, sync. NO vmcnt drain (unlike __syncthreads)
// -> in-flight global loads (x prefetch) and stores (io) cross the barrier.
__device__ __forceinline__ void barrier_fast() {
  asm volatile("s_waitcnt lgkmcnt(0)" ::: "memory");
  __builtin_amdgcn_s_barrier();
  asm volatile("" ::: "memory");
}

// split 4 f32 into bf16-hi (truncated) and bf16-lo (rounded residual), packed 2-per-u32
__device__ __forceinline__ void pack4(float x0, float x1, float x2, float x3,
                                      unsigned &h0, unsigned &h1,
                                      unsigned &l0, unsigned &l1) {
  unsigned a0 = __float_as_uint(x0), a1 = __float_as_uint(x1);
  unsigned a2 = __float_as_uint(x2), a3 = __float_as_uint(x3);
  h0 = __builtin_amdgcn_perm(a1, a0, 0x07060302u);   // {bf16(x1), bf16(x0)}
  h1 = __builtin_amdgcn_perm(a3, a2, 0x07060302u);
  float r0 = x0 - __uint_as_float(a0 & 0xFFFF0000u);
  float r1 = x1 - __uint_as_float(a1 & 0xFFFF0000u);
  float r2 = x2 - __uint_as_float(a2 & 0xFFFF0000u);
  float r3 = x3 - __uint_as_float(a3 & 0xFFFF0000u);
  asm("v_cvt_pk_bf16_f32 %0, %1, %2" : "=v"(l0) : "v"(r0), "v"(r1));
  asm("v_cvt_pk_bf16_f32 %0, %1, %2" : "=v"(l1) : "v"(r2), "v"(r3));
}

__device__ __forceinline__ void pack_frag(float4 v0, float4 v1, bf16x8 &hi, bf16x8 &lo) {
  int4 h4, l4;
  pack4(v0.x, v0.y, v0.z, v0.w, (unsigned&)h4.x, (unsigned&)h4.y, (unsigned&)l4.x, (unsigned&)l4.y);
  pack4(v1.x, v1.y, v1.z, v1.w, (unsigned&)h4.z, (unsigned&)h4.w, (unsigned&)l4.z, (unsigned&)l4.w);
  hi = __builtin_bit_cast(bf16x8, h4);
  lo = __builtin_bit_cast(bf16x8, l4);
}

__device__ __forceinline__ void load_wfrag(const float* p, bf16x8 &hi, bf16x8 &lo) {
  float4 v0 = *(const float4*)p;
  float4 v1 = *(const float4*)(p + 4);
  pack_frag(v0, v1, hi, lo);
}

// ---------------- single persistent MFMA kernel (round-6 structure, raw barriers) ----------------
// 256 blocks (1/CU) x 8 waves, BB=2, 3 raw barriers/step, 42 MFMA per wave per step.
// P1 (all): MLP1 30 MFMA -> a_s         (w4-7 also issue raw x[t+1] loads at top)
// P2: w0-3: RNN 6 + MLP2-kt23 6 -> hobs,m2p (regs) | w4-7: MLP2-kt01 6 -> hm_s
// P3: w0-3: finalize h_t, io write, stage B1lds    | w4-7: pack x[t+1], XIN 6 -> xin_s
__global__ __launch_bounds__(NTHR, 2) void seq_kernel(
    const float* __restrict__ x,    float* __restrict__ io,
    const float* __restrict__ h0g,
    const float* __restrict__ W_in, const float* __restrict__ b_in,
    const float* __restrict__ W_hh, const float* __restrict__ b_hh,
    const float* __restrict__ W1,   const float* __restrict__ b1,
    const float* __restrict__ W2,   const float* __restrict__ b2) {

  __shared__ __align__(16) short B1lds[2048];   // newest-h frag staging
  __shared__ __align__(16) short a_s[544];      // relu(mlp1) bf16, col stride 264
  __shared__ __align__(16) float hm_s[128];     // mlp2 kt01 partial [col2][h64]
  __shared__ __align__(16) float xin_s[128];    // xin(t+1) incl biases [col2][h64]

  const int tid  = threadIdx.x;
  const int w    = tid >> 6;
  const int lane = tid & 63;
  const int q15  = lane & 15;
  const int g    = lane >> 4;
  const int b0   = blockIdx.x * BB;
  const bool gA  = (w < 4);
  const int r0c  = 16*(w & 3) + 4*g;   // 64-row base (RNN / MLP2 / h / xin)
  const int f0   = 16*w + 4*g;         // 128-row base (MLP1)
  const int c01  = q15 & 1;

  const int aW  = q15*264 + f0;        // a_s write (hi), +128 lo; q15<2 only
  const int aRb = c01*264 + 8*g;       // a_s read base (+kt*32, +128 lo)
  const int bWH = (r0c>>5)*1024 + ((r0c>>3)&3)*128 + q15*8 + (r0c&7);
  const int bRD = g*128 + q15*8;

  const f32x4 vz = {0.f, 0.f, 0.f, 0.f};

  // ---- weight fragments ----
  bf16x8 w1h[10], w1l[10];
#pragma unroll
  for (int jt = 0; jt < 10; ++jt)
    load_wfrag(W1 + (size_t)(16*w + q15)*KH + jt*32 + 8*g, w1h[jt], w1l[jt]);

  bf16x8 wxh[4], wxl[4];
  f32x4 biasv = vz, b2r = vz;
  f32x4 b1r = *(const f32x4*)(b1 + f0);
  if (gA) {
    // [0,1]=W_hh kt0,1 ; [2,3]=W2 rows 16w, kt2,3
#pragma unroll
    for (int kt = 0; kt < 2; ++kt) {
      load_wfrag(W_hh + (size_t)(16*w + q15)*HID  + kt*32 + 8*g,       wxh[kt],   wxl[kt]);
      load_wfrag(W2   + (size_t)(16*w + q15)*FEAT + (2+kt)*32 + 8*g,   wxh[2+kt], wxl[2+kt]);
    }
    b2r = *(const f32x4*)(b2 + r0c);
  } else {
    // [0,1]=W2 rows 16(w-4), kt0,1 ; [2,3]=W_in kt0,1
#pragma unroll
    for (int kt = 0; kt < 2; ++kt) {
      load_wfrag(W2   + (size_t)(16*(w-4) + q15)*FEAT + kt*32 + 8*g,   wxh[kt],   wxl[kt]);
      load_wfrag(W_in + (size_t)(16*(w-4) + q15)*INPD + kt*32 + 8*g,   wxh[2+kt], wxl[2+kt]);
    }
    biasv = *(const f32x4*)(b_in + r0c) + *(const f32x4*)(b_hh + r0c);
  }

  for (int i = tid; i < 1024; i += NTHR) ((unsigned*)B1lds)[i] = 0u;
  __syncthreads();

  // ---- state init ----
  f32x4 hprev = vz;
  if (gA) {
    if (q15 < 2) {
      hprev = *(const f32x4*)(h0g + (size_t)(b0 + q15)*HID + r0c);
      unsigned n0, n1, n2, n3;
      pack4(hprev.x, hprev.y, hprev.z, hprev.w, n0, n1, n2, n3);
      *(uint2*)&B1lds[bWH]       = make_uint2(n0, n1);
      *(uint2*)&B1lds[bWH + 512] = make_uint2(n2, n3);
    }
  } else {
    // xin for t=0
    const float* xp = x + (size_t)(b0 + c01)*INPD + 8*g;
    float4 v0 = *(const float4*)xp;        float4 v1 = *(const float4*)(xp + 4);
    float4 v2 = *(const float4*)(xp + 32); float4 v3 = *(const float4*)(xp + 36);
    bf16x8 th0, tl0, th1, tl1;
    pack_frag(v0, v1, th0, tl0);
    pack_frag(v2, v3, th1, tl1);
    f32x4 dhh = biasv, dhl = vz, dlh = vz;
    dhh = MFMA(wxh[2], th0, dhh); dhh = MFMA(wxh[3], th1, dhh);
    dhl = MFMA(wxh[2], tl0, dhl); dhl = MFMA(wxh[3], tl1, dhl);
    dlh = MFMA(wxl[2], th0, dlh); dlh = MFMA(wxl[3], th1, dlh);
    f32x4 xi = (dhh + dhl) + dlh;
    if (q15 < 2) *(f32x4*)&xin_s[q15*64 + r0c] = xi;
  }

  bf16x8 rbh[KEEP][2], rbl[KEEP][2];
  const bf16x8 z8 = {0,0,0,0,0,0,0,0};
#pragma unroll
  for (int s = 0; s < KEEP; ++s) {
    rbh[s][0] = z8; rbl[s][0] = z8; rbh[s][1] = z8; rbl[s][1] = z8;
  }
  __syncthreads();

  int t5 = 0;
  auto step = [&](auto pc) {
    constexpr int ph = decltype(pc)::v;
    constexpr int sN = (ph + 4) % 5;           // slot of h_{t-1}
    const int t = t5 + ph;

    // ---- P1 ----
    float4 xr0, xr1, xr2, xr3;                 // w4-7: raw x[t+1], consumed in P3
    if (!gA) {
      const int tn = (t + 1 < TSTEPS) ? t + 1 : t;
      const float* xp = x + (size_t)tn*BATCH*INPD + (size_t)(b0 + c01)*INPD + 8*g;
      xr0 = *(const float4*)xp;        xr1 = *(const float4*)(xp + 4);
      xr2 = *(const float4*)(xp + 32); xr3 = *(const float4*)(xp + 36);
    }

    rbh[sN][0] = *(const bf16x8*)&B1lds[bRD];
    rbl[sN][0] = *(const bf16x8*)&B1lds[bRD + 512];
    rbh[sN][1] = *(const bf16x8*)&B1lds[bRD + 1024];
    rbl[sN][1] = *(const bf16x8*)&B1lds[bRD + 1536];

    // MLP1: K=320, 5 slots x 2 ktiles, 3-product split; newest slot last
    f32x4 chh = vz, chl = vz, clh = vz;
#pragma unroll
    for (int e = 1; e <= 5; ++e) {
      const int s = (sN + e) % 5;
      const int r = ((s - ph) % 5 + 5) % 5;
#pragma unroll
      for (int q = 0; q < 2; ++q) {
        const int jt = 2*r + q;
        chh = MFMA(w1h[jt], rbh[s][q], chh);
        chl = MFMA(w1h[jt], rbl[s][q], chl);
        clh = MFMA(w1l[jt], rbh[s][q], clh);
      }
    }
    {
      f32x4 apre = (chh + chl) + (clh + b1r);
      f32x4 av = __builtin_elementwise_max(apre, vz);
      unsigned p0, p1, p2, p3;
      pack4(av.x, av.y, av.z, av.w, p0, p1, p2, p3);
      if (q15 < 2) {
        *(uint2*)&a_s[aW]       = make_uint2(p0, p1);
        *(uint2*)&a_s[aW + 128] = make_uint2(p2, p3);
      }
    }
    barrier_fast();   // bar A: a_s ready (x loads stay in flight)

    // ---- P2 ----
    f32x4 hobs = vz, m2p = vz;
    if (gA) {
      bf16x8 ah2 = *(const bf16x8*)&a_s[aRb +  64];
      bf16x8 ah3 = *(const bf16x8*)&a_s[aRb +  96];
      bf16x8 al2 = *(const bf16x8*)&a_s[aRb + 192];
      bf16x8 al3 = *(const bf16x8*)&a_s[aRb + 224];
      f32x4 xinv = vz;
      if (q15 < 2) xinv = *(const f32x4*)&xin_s[q15*64 + r0c];
      // RNN on newest frag (register operands, overlap a_s latency)
      f32x4 dhh = vz, dhl = vz, dlh = vz;
      dhh = MFMA(wxh[0], rbh[sN][0], dhh); dhh = MFMA(wxh[1], rbh[sN][1], dhh);
      dhl = MFMA(wxh[0], rbl[sN][0], dhl); dhl = MFMA(wxh[1], rbl[sN][1], dhl);
      dlh = MFMA(wxl[0], rbh[sN][0], dlh); dlh = MFMA(wxl[1], rbh[sN][1], dlh);
      // MLP2 kt2,3 partial (stays in registers)
      f32x4 mhh = vz, mhl = vz, mlh = vz;
      mhh = MFMA(wxh[2], ah2, mhh); mhh = MFMA(wxh[3], ah3, mhh);
      mhl = MFMA(wxh[2], al2, mhl); mhl = MFMA(wxh[3], al3, mhl);
      mlh = MFMA(wxl[2], ah2, mlh); mlh = MFMA(wxl[3], ah3, mlh);
      m2p = (mhh + mhl) + mlh;
      f32x4 pre = (dhh + dhl) + dlh + xinv;    // xin includes biases
      f32x4 rl = __builtin_elementwise_max(pre, vz);
      hobs = hprev * (1.f - ALPHA) + rl * ALPHA;
    } else {
      bf16x8 ah0 = *(const bf16x8*)&a_s[aRb +   0];
      bf16x8 ah1 = *(const bf16x8*)&a_s[aRb +  32];
      bf16x8 al0 = *(const bf16x8*)&a_s[aRb + 128];
      bf16x8 al1 = *(const bf16x8*)&a_s[aRb + 160];
      f32x4 mhh = vz, mhl = vz, mlh = vz;
      mhh = MFMA(wxh[0], ah0, mhh); mhh = MFMA(wxh[1], ah1, mhh);
      mhl = MFMA(wxh[0], al0, mhl); mhl = MFMA(wxh[1], al1, mhl);
      mlh = MFMA(wxl[0], ah0, mlh); mlh = MFMA(wxl[1], ah1, mlh);
      f32x4 hmv = (mhh + mhl) + mlh;
      if (q15 < 2) *(f32x4*)&hm_s[q15*64 + r0c] = hmv;
    }
    barrier_fast();   // bar B: hm_s ready

    // ---- P3 ----
    if (gA) {
      f32x4 hmo = vz;
      if (q15 < 2) hmo = *(const f32x4*)&hm_s[q15*64 + r0c];
      f32x4 hm = hmo + m2p + b2r;
      f32x4 hn = (t >= KEEP) ? (hobs + hm) * 0.5f : hobs;
      if (q15 < 2) {
        *(f32x4*)(io + (size_t)t*BATCH*HID + (size_t)(b0 + q15)*HID + r0c) = hn;
        if (t == TSTEPS-1)
          *(f32x4*)(io + (size_t)TSTEPS*BATCH*HID + (size_t)(b0 + q15)*HID + r0c) = hn;
        unsigned n0, n1, n2, n3;
        pack4(hn.x, hn.y, hn.z, hn.w, n0, n1, n2, n3);
        *(uint2*)&B1lds[bWH]       = make_uint2(n0, n1);
        *(uint2*)&B1lds[bWH + 512] = make_uint2(n2, n3);
      }
      hprev = hn;
    } else {
      bf16x8 th0, tl0, th1, tl1;
      pack_frag(xr0, xr1, th0, tl0);       // x[t+1], ~2 phases of async cover
      pack_frag(xr2, xr3, th1, tl1);
      f32x4 dhh = biasv, dhl = vz, dlh = vz;
      dhh = MFMA(wxh[2], th0, dhh); dhh = MFMA(wxh[3], th1, dhh);
      dhl = MFMA(wxh[2], tl0, dhl); dhl = MFMA(wxh[3], tl1, dhl);
      dlh = MFMA(wxl[2], th0, dlh); dlh = MFMA(wxl[3], th1, dlh);
      f32x4 xi = (dhh + dhl) + dlh;
      if (q15 < 2) *(f32x4*)&xin_s[q15*64 + r0c] = xi;
    }
    barrier_fast();   // bar C: B1lds + xin_s staged
  };

  for (t5 = 0; t5 < TSTEPS; t5 += 5) {
    step(IC<0>{});
    step(IC<1>{});
    step(IC<2>{});
    step(IC<3>{});
    step(IC<4>{});
  }
}

extern "C" void kernel_launch(void* const* d_in, const int* in_sizes, int n_in,
                              void* d_out, int out_size, void* d_ws, size_t ws_size,
                              hipStream_t stream) {
  (void)in_sizes; (void)n_in; (void)out_size; (void)d_ws; (void)ws_size;
  const float* x    = (const float*)d_in[0];
  const float* h0   = (const float*)d_in[1];
  const float* W_in = (const float*)d_in[2];
  const float* b_in = (const float*)d_in[3];
  const float* W_hh = (const float*)d_in[4];
  const float* b_hh = (const float*)d_in[5];
  const float* W1   = (const float*)d_in[6];
  const float* b1   = (const float*)d_in[7];
  const float* W2   = (const float*)d_in[8];
  const float* b2   = (const float*)d_in[9];
  float* out = (float*)d_out;

  seq_kernel<<<NBLK, NTHR, 0, stream>>>(x, out, h0, W_in, b_in, W_hh, b_hh, W1, b1, W2, b2);
}

// Round 11
// 1158.848 us; speedup vs baseline: 2.3320x; 1.0518x over previous
//
#include <hip/hip_runtime.h>

typedef short bf16x8 __attribute__((ext_vector_type(8)));
typedef float f32x4  __attribute__((ext_vector_type(4)));

#define TSTEPS 1000
#define BATCH  512
#define HID    64
#define INPD   64
#define FEAT   128
#define KEEP   5
#define KH     320
#define ALPHA  0.2f
#define BB     2
#define NBLK   (BATCH/BB)   // 256
#define NTHR   512

#define MFMA(a,b,c) __builtin_amdgcn_mfma_f32_16x16x32_bf16(a, b, c, 0, 0, 0)

template<int P> struct IC { static constexpr int v = P; };

// Raw barrier: flush own LDS writes, sync. No vmcnt drain.
__device__ __forceinline__ void barrier_fast() {
  asm volatile("s_waitcnt lgkmcnt(0)" ::: "memory");
  __builtin_amdgcn_s_barrier();
  asm volatile("" ::: "memory");
}

// hi/lo column fold: acc columns (0,1)=hi-B products, (2,3)=lo-B products.
// total[col c] = acc[c] + acc[c^2]  (valid in lanes q15<2; dup in 2,3)
__device__ __forceinline__ f32x4 fold2(f32x4 v) {
  f32x4 r;
  r.x = v.x + __shfl_xor(v.x, 2);
  r.y = v.y + __shfl_xor(v.y, 2);
  r.z = v.z + __shfl_xor(v.z, 2);
  r.w = v.w + __shfl_xor(v.w, 2);
  return r;
}

// split 4 f32 into bf16-hi (truncated) and bf16-lo (rounded residual), packed 2-per-u32
__device__ __forceinline__ void pack4(float x0, float x1, float x2, float x3,
                                      unsigned &h0, unsigned &h1,
                                      unsigned &l0, unsigned &l1) {
  unsigned a0 = __float_as_uint(x0), a1 = __float_as_uint(x1);
  unsigned a2 = __float_as_uint(x2), a3 = __float_as_uint(x3);
  h0 = __builtin_amdgcn_perm(a1, a0, 0x07060302u);
  h1 = __builtin_amdgcn_perm(a3, a2, 0x07060302u);
  float r0 = x0 - __uint_as_float(a0 & 0xFFFF0000u);
  float r1 = x1 - __uint_as_float(a1 & 0xFFFF0000u);
  float r2 = x2 - __uint_as_float(a2 & 0xFFFF0000u);
  float r3 = x3 - __uint_as_float(a3 & 0xFFFF0000u);
  asm("v_cvt_pk_bf16_f32 %0, %1, %2" : "=v"(l0) : "v"(r0), "v"(r1));
  asm("v_cvt_pk_bf16_f32 %0, %1, %2" : "=v"(l1) : "v"(r2), "v"(r3));
}

__device__ __forceinline__ void pack_frag(float4 v0, float4 v1, bf16x8 &hi, bf16x8 &lo) {
  int4 h4, l4;
  pack4(v0.x, v0.y, v0.z, v0.w, (unsigned&)h4.x, (unsigned&)h4.y, (unsigned&)l4.x, (unsigned&)l4.y);
  pack4(v1.x, v1.y, v1.z, v1.w, (unsigned&)h4.z, (unsigned&)h4.w, (unsigned&)l4.z, (unsigned&)l4.w);
  hi = __builtin_bit_cast(bf16x8, h4);
  lo = __builtin_bit_cast(bf16x8, l4);
}

__device__ __forceinline__ void load_wfrag(const float* p, bf16x8 &hi, bf16x8 &lo) {
  float4 v0 = *(const float4*)p;
  float4 v1 = *(const float4*)(p + 4);
  pack_frag(v0, v1, hi, lo);
}

// ---------------- single persistent MFMA kernel, hi/lo COLUMN-PACKED, 2 barriers/step ----------------
// B-fragments: cols {0,1} = (b0,b1) hi, cols {2,3} = (b0,b1) lo. Per K-tile: 2 MFMA
// (A=Wh, A=Wl) + cross-lane fold. 224 MFMA/CU-step; ring regs halved vs 3-product split.
// P1 (all): MLP1 20 MFMA -> a_s
//     gB additionally: issue raw x[t+2]; pack x[t+1]; XIN 4 -> xin_s[(t+1)&1]
//                                                                   bar A
// P2: gA: RNN 4 + MLP2 full-K 8; finalize h_t; io write; stage B1lds
//     gB: idle                                                      bar B
__global__ __launch_bounds__(NTHR, 2) void seq_kernel(
    const float* __restrict__ x,    float* __restrict__ io,
    const float* __restrict__ h0g,
    const float* __restrict__ W_in, const float* __restrict__ b_in,
    const float* __restrict__ W_hh, const float* __restrict__ b_hh,
    const float* __restrict__ W1,   const float* __restrict__ b1,
    const float* __restrict__ W2,   const float* __restrict__ b2) {

  // B1lds: addr(j,col) = (j>>5)*512 + ((j>>3)&3)*128 + col*8 + (j&7)   [shorts]
  __shared__ __align__(16) short B1lds[1024];
  // a_s: addr(k,col) = (k>>5)*128 + ((k>>3)&3)*32 + col*8 + (k&7)      [shorts], 4 cols
  __shared__ __align__(16) short a_s[512];
  __shared__ __align__(16) float xin_s[2][128];  // xin incl biases [par][col2*64+h]

  const int tid  = threadIdx.x;
  const int w    = tid >> 6;
  const int lane = tid & 63;
  const int q15  = lane & 15;
  const int g    = lane >> 4;
  const int b0   = blockIdx.x * BB;
  const bool gA  = (w < 4);
  const int r0c  = 16*(w & 3) + 4*g;   // 64-row base (RNN / MLP2 / h / xin)
  const int f0   = 16*w + 4*g;         // 128-row base (MLP1)
  const int c01  = q15 & 1;

  // a_s writer (hi at col q15, lo at col q15+2 = +16 shorts); rows k=f0..f0+3
  const int aWH = (w>>1)*128 + (2*(w&1) + (g>>1))*32 + q15*8 + 4*(g&1);
  const int aRD = g*32 + (q15 & 3)*8;            // + kt*128, b128 read
  // B1lds writer (rows j=r0c..r0c+3) / reader
  const int bWH = ((w&3)>>1)*512 + ((2*(w&3) + (g>>1)) & 3)*128 + q15*8 + 4*(g&1);
  const int bRD = g*128 + q15*8;                 // + q*512

  const f32x4 vz = {0.f, 0.f, 0.f, 0.f};
  const bf16x8 z8 = {0,0,0,0,0,0,0,0};

  // ---- weight fragments ----
  bf16x8 w1h[10], w1l[10];
#pragma unroll
  for (int jt = 0; jt < 10; ++jt)
    load_wfrag(W1 + (size_t)(16*w + q15)*KH + jt*32 + 8*g, w1h[jt], w1l[jt]);

  // shared union: gA: [0,1]=W_hh kt0-1, [2..5]=W2 kt0-3 ; gB: [0,1]=W_in kt0-1
  bf16x8 wxh[6], wxl[6];
#pragma unroll
  for (int i = 0; i < 6; ++i) { wxh[i] = z8; wxl[i] = z8; }
  f32x4 biasv = vz, b2r = vz;
  f32x4 b1r = *(const f32x4*)(b1 + f0);
  if (gA) {
#pragma unroll
    for (int kt = 0; kt < 2; ++kt)
      load_wfrag(W_hh + (size_t)(16*w + q15)*HID + kt*32 + 8*g, wxh[kt], wxl[kt]);
#pragma unroll
    for (int kt = 0; kt < 4; ++kt)
      load_wfrag(W2 + (size_t)(16*w + q15)*FEAT + kt*32 + 8*g, wxh[2+kt], wxl[2+kt]);
    b2r = *(const f32x4*)(b2 + r0c);
  } else {
#pragma unroll
    for (int kt = 0; kt < 2; ++kt)
      load_wfrag(W_in + (size_t)(16*(w-4) + q15)*INPD + kt*32 + 8*g, wxh[kt], wxl[kt]);
    biasv = *(const f32x4*)(b_in + r0c) + *(const f32x4*)(b_hh + r0c);
  }

  for (int i = tid; i < 512; i += NTHR) ((unsigned*)B1lds)[i] = 0u;  // cols 4-15 stay 0 forever
  __syncthreads();

  // ---- state init ----
  f32x4 hprev = vz;
  float4 xc0, xc1, xc2, xc3;            // raw x[t+1] (gB)
  if (gA) {
    if (q15 < 2) {
      hprev = *(const f32x4*)(h0g + (size_t)(b0 + q15)*HID + r0c);
      unsigned n0, n1, n2, n3;
      pack4(hprev.x, hprev.y, hprev.z, hprev.w, n0, n1, n2, n3);
      *(uint2*)&B1lds[bWH]      = make_uint2(n0, n1);   // hi  -> col q15
      *(uint2*)&B1lds[bWH + 16] = make_uint2(n2, n3);   // lo  -> col q15+2
    }
  } else {
    // xin for t=0 -> xin_s[0]
    const float* xp = x + (size_t)(b0 + c01)*INPD + 8*g;
    float4 v0 = *(const float4*)xp;        float4 v1 = *(const float4*)(xp + 4);
    float4 v2 = *(const float4*)(xp + 32); float4 v3 = *(const float4*)(xp + 36);
    bf16x8 th0, tl0, th1, tl1;
    pack_frag(v0, v1, th0, tl0);
    pack_frag(v2, v3, th1, tl1);
    bf16x8 f0b = (q15 & 2) ? tl0 : th0;
    bf16x8 f1b = (q15 & 2) ? tl1 : th1;
    f32x4 aH = vz, aL = vz;
    aH = MFMA(wxh[0], f0b, aH); aH = MFMA(wxh[1], f1b, aH);
    aL = MFMA(wxl[0], f0b, aL); aL = MFMA(wxl[1], f1b, aL);
    f32x4 xi = fold2(aH + aL) + biasv;
    if (q15 < 2) *(f32x4*)&xin_s[0][q15*64 + r0c] = xi;
    // preload raw x[1] (consumed in P1 of t=0 for xin_s[1])
    const float* xq = x + (size_t)1*BATCH*INPD + (size_t)(b0 + c01)*INPD + 8*g;
    xc0 = *(const float4*)xq;        xc1 = *(const float4*)(xq + 4);
    xc2 = *(const float4*)(xq + 32); xc3 = *(const float4*)(xq + 36);
  }

  // hidden ring: ONE packed fragment per (slot, ktile) — lane's own column
  bf16x8 rb[KEEP][2];
#pragma unroll
  for (int s = 0; s < KEEP; ++s) { rb[s][0] = z8; rb[s][1] = z8; }
  __syncthreads();

  int t5 = 0;
  auto step = [&](auto pc) {
    constexpr int ph = decltype(pc)::v;
    constexpr int sN = (ph + 4) % 5;           // slot of h_{t-1}
    const int t = t5 + ph;

    // ---- P1 ----
    float4 xn0, xn1, xn2, xn3;                 // gB: raw x[t+2], consumed next step's P1
    if (!gA) {
      int tn = t + 2; if (tn > TSTEPS-1) tn = TSTEPS-1;
      const float* xp = x + (size_t)tn*BATCH*INPD + (size_t)(b0 + c01)*INPD + 8*g;
      xn0 = *(const float4*)xp;        xn1 = *(const float4*)(xp + 4);
      xn2 = *(const float4*)(xp + 32); xn3 = *(const float4*)(xp + 36);
    }

    rb[sN][0] = *(const bf16x8*)&B1lds[bRD];
    rb[sN][1] = *(const bf16x8*)&B1lds[bRD + 512];

    // MLP1: K=320, 5 slots x 2 ktiles, hi/lo column-packed: 2 MFMA/ktile
    f32x4 aH = vz, aL = vz;
#pragma unroll
    for (int e = 1; e <= 5; ++e) {
      const int s = (sN + e) % 5;               // newest (sN) last
      const int r = ((s - ph) % 5 + 5) % 5;     // age rank
#pragma unroll
      for (int q = 0; q < 2; ++q) {
        const int jt = 2*r + q;
        aH = MFMA(w1h[jt], rb[s][q], aH);
        aL = MFMA(w1l[jt], rb[s][q], aL);
      }
    }
    {
      f32x4 apre = fold2(aH + aL) + b1r;
      f32x4 av = __builtin_elementwise_max(apre, vz);
      unsigned p0, p1, p2, p3;
      pack4(av.x, av.y, av.z, av.w, p0, p1, p2, p3);
      if (q15 < 2) {
        *(uint2*)&a_s[aWH]      = make_uint2(p0, p1);   // hi -> col q15
        *(uint2*)&a_s[aWH + 16] = make_uint2(p2, p3);   // lo -> col q15+2
      }
    }

    // gB: x-stage for step t+1 (xc = x[t+1], loaded in previous step's P1)
    if (!gA) {
      bf16x8 th0, tl0, th1, tl1;
      pack_frag(xc0, xc1, th0, tl0);
      pack_frag(xc2, xc3, th1, tl1);
      bf16x8 f0b = (q15 & 2) ? tl0 : th0;
      bf16x8 f1b = (q15 & 2) ? tl1 : th1;
      f32x4 xH = vz, xL = vz;
      xH = MFMA(wxh[0], f0b, xH); xH = MFMA(wxh[1], f1b, xH);
      xL = MFMA(wxl[0], f0b, xL); xL = MFMA(wxl[1], f1b, xL);
      f32x4 xi = fold2(xH + xL) + biasv;
      if (q15 < 2) *(f32x4*)&xin_s[(t + 1) & 1][q15*64 + r0c] = xi;
      xc0 = xn0; xc1 = xn1; xc2 = xn2; xc3 = xn3;
    }
    barrier_fast();   // bar A: a_s + xin_s[(t+1)&1] ready

    // ---- P2 ----
    if (gA) {
      bf16x8 af0 = *(const bf16x8*)&a_s[aRD +   0];
      bf16x8 af1 = *(const bf16x8*)&a_s[aRD + 128];
      bf16x8 af2 = *(const bf16x8*)&a_s[aRD + 256];
      bf16x8 af3 = *(const bf16x8*)&a_s[aRD + 384];
      f32x4 xinv = *(const f32x4*)&xin_s[t & 1][(q15 & 1)*64 + r0c];
      // RNN on newest packed frag (register operands, overlap a_s latency)
      f32x4 rH = vz, rL = vz;
      rH = MFMA(wxh[0], rb[sN][0], rH); rH = MFMA(wxh[1], rb[sN][1], rH);
      rL = MFMA(wxl[0], rb[sN][0], rL); rL = MFMA(wxl[1], rb[sN][1], rL);
      // MLP2 full K, packed
      f32x4 mH = vz, mL = vz;
      mH = MFMA(wxh[2], af0, mH); mL = MFMA(wxl[2], af0, mL);
      mH = MFMA(wxh[3], af1, mH); mL = MFMA(wxl[3], af1, mL);
      mH = MFMA(wxh[4], af2, mH); mL = MFMA(wxl[4], af2, mL);
      mH = MFMA(wxh[5], af3, mH); mL = MFMA(wxl[5], af3, mL);
      f32x4 pre = fold2(rH + rL) + xinv;       // xin includes biases
      f32x4 rl_ = __builtin_elementwise_max(pre, vz);
      f32x4 hobs = hprev * (1.f - ALPHA) + rl_ * ALPHA;
      f32x4 hm = fold2(mH + mL) + b2r;
      f32x4 hn = (t >= KEEP) ? (hobs + hm) * 0.5f : hobs;
      if (q15 < 2) {
        *(f32x4*)(io + (size_t)t*BATCH*HID + (size_t)(b0 + q15)*HID + r0c) = hn;
        if (t == TSTEPS-1)
          *(f32x4*)(io + (size_t)TSTEPS*BATCH*HID + (size_t)(b0 + q15)*HID + r0c) = hn;
        unsigned n0, n1, n2, n3;
        pack4(hn.x, hn.y, hn.z, hn.w, n0, n1, n2, n3);
        *(uint2*)&B1lds[bWH]      = make_uint2(n0, n1);   // hi -> col q15
        *(uint2*)&B1lds[bWH + 16] = make_uint2(n2, n3);   // lo -> col q15+2
      }
      hprev = hn;
    }
    barrier_fast();   // bar B: B1lds staged
  };

  for (t5 = 0; t5 < TSTEPS; t5 += 5) {
    step(IC<0>{});
    step(IC<1>{});
    step(IC<2>{});
    step(IC<3>{});
    step(IC<4>{});
  }
}

extern "C" void kernel_launch(void* const* d_in, const int* in_sizes, int n_in,
                              void* d_out, int out_size, void* d_ws, size_t ws_size,
                              hipStream_t stream) {
  (void)in_sizes; (void)n_in; (void)out_size; (void)d_ws; (void)ws_size;
  const float* x    = (const float*)d_in[0];
  const float* h0   = (const float*)d_in[1];
  const float* W_in = (const float*)d_in[2];
  const float* b_in = (const float*)d_in[3];
  const float* W_hh = (const float*)d_in[4];
  const float* b_hh = (const float*)d_in[5];
  const float* W1   = (const float*)d_in[6];
  const float* b1   = (const float*)d_in[7];
  const float* W2   = (const float*)d_in[8];
  const float* b2   = (const float*)d_in[9];
  float* out = (float*)d_out;

  seq_kernel<<<NBLK, NTHR, 0, stream>>>(x, out, h0, W_in, b_in, W_hh, b_hh, W1, b1, W2, b2);
}

// Round 12
// 974.296 us; speedup vs baseline: 2.7738x; 1.1894x over previous
//
#include <hip/hip_runtime.h>

typedef short bf16x8 __attribute__((ext_vector_type(8)));
typedef float f32x4  __attribute__((ext_vector_type(4)));

#define TSTEPS 1000
#define BATCH  512
#define HID    64
#define INPD   64
#define FEAT   128
#define KEEP   5
#define KH     320
#define ALPHA  0.2f
#define BB     2
#define NBLK   (BATCH/BB)   // 256
#define NTHR   512

#define MFMA(a,b,c) __builtin_amdgcn_mfma_f32_16x16x32_bf16(a, b, c, 0, 0, 0)

template<int P> struct IC { static constexpr int v = P; };

// Raw barrier: flush own LDS writes, sync. No vmcnt drain.
__device__ __forceinline__ void barrier_fast() {
  asm volatile("s_waitcnt lgkmcnt(0)" ::: "memory");
  __builtin_amdgcn_s_barrier();
  asm volatile("" ::: "memory");
}

// hi/lo column fold: acc columns (0,1)=hi-B products, (2,3)=lo-B products.
// total[col c] = acc[c] + acc[c^2]  (valid in lanes q15<2; dup in 2,3)
__device__ __forceinline__ f32x4 fold2(f32x4 v) {
  f32x4 r;
  r.x = v.x + __shfl_xor(v.x, 2);
  r.y = v.y + __shfl_xor(v.y, 2);
  r.z = v.z + __shfl_xor(v.z, 2);
  r.w = v.w + __shfl_xor(v.w, 2);
  return r;
}

// split 4 f32 into bf16-hi (truncated) and bf16-lo (rounded residual), packed 2-per-u32
__device__ __forceinline__ void pack4(float x0, float x1, float x2, float x3,
                                      unsigned &h0, unsigned &h1,
                                      unsigned &l0, unsigned &l1) {
  unsigned a0 = __float_as_uint(x0), a1 = __float_as_uint(x1);
  unsigned a2 = __float_as_uint(x2), a3 = __float_as_uint(x3);
  h0 = __builtin_amdgcn_perm(a1, a0, 0x07060302u);
  h1 = __builtin_amdgcn_perm(a3, a2, 0x07060302u);
  float r0 = x0 - __uint_as_float(a0 & 0xFFFF0000u);
  float r1 = x1 - __uint_as_float(a1 & 0xFFFF0000u);
  float r2 = x2 - __uint_as_float(a2 & 0xFFFF0000u);
  float r3 = x3 - __uint_as_float(a3 & 0xFFFF0000u);
  asm("v_cvt_pk_bf16_f32 %0, %1, %2" : "=v"(l0) : "v"(r0), "v"(r1));
  asm("v_cvt_pk_bf16_f32 %0, %1, %2" : "=v"(l1) : "v"(r2), "v"(r3));
}

__device__ __forceinline__ void pack_frag(float4 v0, float4 v1, bf16x8 &hi, bf16x8 &lo) {
  int4 h4, l4;
  pack4(v0.x, v0.y, v0.z, v0.w, (unsigned&)h4.x, (unsigned&)h4.y, (unsigned&)l4.x, (unsigned&)l4.y);
  pack4(v1.x, v1.y, v1.z, v1.w, (unsigned&)h4.z, (unsigned&)h4.w, (unsigned&)l4.z, (unsigned&)l4.w);
  hi = __builtin_bit_cast(bf16x8, h4);
  lo = __builtin_bit_cast(bf16x8, l4);
}

__device__ __forceinline__ void load_wfrag(const float* p, bf16x8 &hi, bf16x8 &lo) {
  float4 v0 = *(const float4*)p;
  float4 v1 = *(const float4*)(p + 4);
  pack_frag(v0, v1, hi, lo);
}

// ---------------- packed-column MFMA kernel, carried MLP1 accumulator ----------------
// B-fragments: cols {0,1}=(b0,b1) hi, {2,3}=(b0,b1) lo. 2 MFMA/K-tile + fold.
// The 16 old-slot MLP1 MFMAs for step t+1 are computed in P2(t) (no h_t dep);
// P1 holds ONLY the newest-slot pair -> short critical phase.
// P1 (all): read h_{t-1} frag; 4 MFMA into carried acc; fold/relu/pack -> a_s.  bar A
// P2: gA: a_s reads; 16 old-MLP1(t+1); RNN 4; MLP2 8; finalize h_t; io; stage B1lds
//     gB: issue x[t+2]; 16 old-MLP1(t+1); pack x[t+1]; XIN 4 -> xin_s[(t+1)&1]  bar B
__global__ __launch_bounds__(NTHR, 2) void seq_kernel(
    const float* __restrict__ x,    float* __restrict__ io,
    const float* __restrict__ h0g,
    const float* __restrict__ W_in, const float* __restrict__ b_in,
    const float* __restrict__ W_hh, const float* __restrict__ b_hh,
    const float* __restrict__ W1,   const float* __restrict__ b1,
    const float* __restrict__ W2,   const float* __restrict__ b2) {

  // B1lds: addr(j,col) = (j>>5)*512 + ((j>>3)&3)*128 + col*8 + (j&7)   [shorts]
  __shared__ __align__(16) short B1lds[1024];
  // a_s: addr(k,col) = (k>>5)*128 + ((k>>3)&3)*32 + col*8 + (k&7)      [shorts]
  __shared__ __align__(16) short a_s[512];
  __shared__ __align__(16) float xin_s[2][128];  // xin incl biases [par][col2*64+h]

  const int tid  = threadIdx.x;
  const int w    = tid >> 6;
  const int lane = tid & 63;
  const int q15  = lane & 15;
  const int g    = lane >> 4;
  const int b0   = blockIdx.x * BB;
  const bool gA  = (w < 4);
  const int r0c  = 16*(w & 3) + 4*g;   // 64-row base (RNN / MLP2 / h / xin)
  const int f0   = 16*w + 4*g;         // 128-row base (MLP1)
  const int c01  = q15 & 1;

  const int aWH = (w>>1)*128 + (2*(w&1) + (g>>1))*32 + q15*8 + 4*(g&1);
  const int aRD = g*32 + (q15 & 3)*8;            // + kt*128
  const int bWH = ((w&3)>>1)*512 + ((2*(w&3) + (g>>1)) & 3)*128 + q15*8 + 4*(g&1);
  const int bRD = g*128 + q15*8;                 // + q*512

  const f32x4 vz = {0.f, 0.f, 0.f, 0.f};
  const bf16x8 z8 = {0,0,0,0,0,0,0,0};

  // ---- weight fragments ----
  bf16x8 w1h[10], w1l[10];
#pragma unroll
  for (int jt = 0; jt < 10; ++jt)
    load_wfrag(W1 + (size_t)(16*w + q15)*KH + jt*32 + 8*g, w1h[jt], w1l[jt]);

  // gA: [0,1]=W_hh kt0-1, [2..5]=W2 kt0-3 ; gB: [0,1]=W_in kt0-1
  bf16x8 wxh[6], wxl[6];
#pragma unroll
  for (int i = 0; i < 6; ++i) { wxh[i] = z8; wxl[i] = z8; }
  f32x4 biasv = vz, b2r = vz;
  f32x4 b1r = *(const f32x4*)(b1 + f0);
  if (gA) {
#pragma unroll
    for (int kt = 0; kt < 2; ++kt)
      load_wfrag(W_hh + (size_t)(16*w + q15)*HID + kt*32 + 8*g, wxh[kt], wxl[kt]);
#pragma unroll
    for (int kt = 0; kt < 4; ++kt)
      load_wfrag(W2 + (size_t)(16*w + q15)*FEAT + kt*32 + 8*g, wxh[2+kt], wxl[2+kt]);
    b2r = *(const f32x4*)(b2 + r0c);
  } else {
#pragma unroll
    for (int kt = 0; kt < 2; ++kt)
      load_wfrag(W_in + (size_t)(16*(w-4) + q15)*INPD + kt*32 + 8*g, wxh[kt], wxl[kt]);
    biasv = *(const f32x4*)(b_in + r0c) + *(const f32x4*)(b_hh + r0c);
  }

  for (int i = tid; i < 512; i += NTHR) ((unsigned*)B1lds)[i] = 0u;  // cols 4-15 stay 0
  __syncthreads();

  // ---- state init ----
  f32x4 hprev = vz;
  float4 xc0, xc1, xc2, xc3;            // raw x[t+1] (gB)
  if (gA) {
    if (q15 < 2) {
      hprev = *(const f32x4*)(h0g + (size_t)(b0 + q15)*HID + r0c);
      unsigned n0, n1, n2, n3;
      pack4(hprev.x, hprev.y, hprev.z, hprev.w, n0, n1, n2, n3);
      *(uint2*)&B1lds[bWH]      = make_uint2(n0, n1);   // hi  -> col q15
      *(uint2*)&B1lds[bWH + 16] = make_uint2(n2, n3);   // lo  -> col q15+2
    }
  } else {
    // xin for t=0 -> xin_s[0]
    const float* xp = x + (size_t)(b0 + c01)*INPD + 8*g;
    float4 v0 = *(const float4*)xp;        float4 v1 = *(const float4*)(xp + 4);
    float4 v2 = *(const float4*)(xp + 32); float4 v3 = *(const float4*)(xp + 36);
    bf16x8 th0, tl0, th1, tl1;
    pack_frag(v0, v1, th0, tl0);
    pack_frag(v2, v3, th1, tl1);
    bf16x8 f0b = (q15 & 2) ? tl0 : th0;
    bf16x8 f1b = (q15 & 2) ? tl1 : th1;
    f32x4 aHx = vz, aLx = vz;
    aHx = MFMA(wxh[0], f0b, aHx); aHx = MFMA(wxh[1], f1b, aHx);
    aLx = MFMA(wxl[0], f0b, aLx); aLx = MFMA(wxl[1], f1b, aLx);
    f32x4 xi = fold2(aHx + aLx) + biasv;
    if (q15 < 2) *(f32x4*)&xin_s[0][q15*64 + r0c] = xi;
    // preload raw x[1] (packed in P2 of t=0 for xin_s[1])
    const float* xq = x + (size_t)1*BATCH*INPD + (size_t)(b0 + c01)*INPD + 8*g;
    xc0 = *(const float4*)xq;        xc1 = *(const float4*)(xq + 4);
    xc2 = *(const float4*)(xq + 32); xc3 = *(const float4*)(xq + 36);
  }

  // hidden ring: one packed fragment per (slot, ktile)
  bf16x8 rb[KEEP][2];
#pragma unroll
  for (int s = 0; s < KEEP; ++s) { rb[s][0] = z8; rb[s][1] = z8; }

  // carried MLP1 accumulator (ranks 0-3 of the CURRENT step); zero for t=0
  f32x4 aH = vz, aL = vz;
  __syncthreads();

  int t5 = 0;
  auto step = [&](auto pc) {
    constexpr int ph = decltype(pc)::v;
    constexpr int sN = (ph + 4) % 5;           // slot of h_{t-1}
    const int t = t5 + ph;

    // ---- P1 (short): newest-slot MLP1 + publish a_s ----
    rb[sN][0] = *(const bf16x8*)&B1lds[bRD];
    rb[sN][1] = *(const bf16x8*)&B1lds[bRD + 512];

    aH = MFMA(w1h[8], rb[sN][0], aH);
    aL = MFMA(w1l[8], rb[sN][0], aL);
    aH = MFMA(w1h[9], rb[sN][1], aH);
    aL = MFMA(w1l[9], rb[sN][1], aL);
    {
      f32x4 apre = fold2(aH + aL) + b1r;
      f32x4 av = __builtin_elementwise_max(apre, vz);
      unsigned p0, p1, p2, p3;
      pack4(av.x, av.y, av.z, av.w, p0, p1, p2, p3);
      if (q15 < 2) {
        *(uint2*)&a_s[aWH]      = make_uint2(p0, p1);   // hi -> col q15
        *(uint2*)&a_s[aWH + 16] = make_uint2(p2, p3);   // lo -> col q15+2
      }
    }
    barrier_fast();   // bar A: a_s ready

    // ---- P2 ----
    f32x4 nH = vz, nL = vz;   // MLP1 ranks 0-3 for step t+1 (no h_t dependency)
    if (gA) {
      bf16x8 af0 = *(const bf16x8*)&a_s[aRD +   0];
      bf16x8 af1 = *(const bf16x8*)&a_s[aRD + 128];
      bf16x8 af2 = *(const bf16x8*)&a_s[aRD + 256];
      bf16x8 af3 = *(const bf16x8*)&a_s[aRD + 384];
      f32x4 xinv = *(const f32x4*)&xin_s[t & 1][(q15 & 1)*64 + r0c];
      // old-slot MLP1 for t+1 — independent, hides a_s read latency
#pragma unroll
      for (int r = 0; r < 4; ++r) {
        const int s = (ph + 1 + r) % 5;        // compile-time (ph, r static)
        nH = MFMA(w1h[2*r],   rb[s][0], nH);
        nH = MFMA(w1h[2*r+1], rb[s][1], nH);
        nL = MFMA(w1l[2*r],   rb[s][0], nL);
        nL = MFMA(w1l[2*r+1], rb[s][1], nL);
      }
      // RNN on newest frag
      f32x4 rH = vz, rL = vz;
      rH = MFMA(wxh[0], rb[sN][0], rH); rH = MFMA(wxh[1], rb[sN][1], rH);
      rL = MFMA(wxl[0], rb[sN][0], rL); rL = MFMA(wxl[1], rb[sN][1], rL);
      // MLP2 full K
      f32x4 mH = vz, mL = vz;
      mH = MFMA(wxh[2], af0, mH); mL = MFMA(wxl[2], af0, mL);
      mH = MFMA(wxh[3], af1, mH); mL = MFMA(wxl[3], af1, mL);
      mH = MFMA(wxh[4], af2, mH); mL = MFMA(wxl[4], af2, mL);
      mH = MFMA(wxh[5], af3, mH); mL = MFMA(wxl[5], af3, mL);
      f32x4 pre = fold2(rH + rL) + xinv;       // xin includes biases
      f32x4 rl_ = __builtin_elementwise_max(pre, vz);
      f32x4 hobs = hprev * (1.f - ALPHA) + rl_ * ALPHA;
      f32x4 hm = fold2(mH + mL) + b2r;
      f32x4 hn = (t >= KEEP) ? (hobs + hm) * 0.5f : hobs;
      if (q15 < 2) {
        *(f32x4*)(io + (size_t)t*BATCH*HID + (size_t)(b0 + q15)*HID + r0c) = hn;
        if (t == TSTEPS-1)
          *(f32x4*)(io + (size_t)TSTEPS*BATCH*HID + (size_t)(b0 + q15)*HID + r0c) = hn;
        unsigned n0, n1, n2, n3;
        pack4(hn.x, hn.y, hn.z, hn.w, n0, n1, n2, n3);
        *(uint2*)&B1lds[bWH]      = make_uint2(n0, n1);   // hi -> col q15
        *(uint2*)&B1lds[bWH + 16] = make_uint2(n2, n3);   // lo -> col q15+2
      }
      hprev = hn;
    } else {
      // issue raw x[t+2] (consumed at P2(t+1))
      float4 xn0, xn1, xn2, xn3;
      {
        int tn = t + 2; if (tn > TSTEPS-1) tn = TSTEPS-1;
        const float* xp = x + (size_t)tn*BATCH*INPD + (size_t)(b0 + c01)*INPD + 8*g;
        xn0 = *(const float4*)xp;        xn1 = *(const float4*)(xp + 4);
        xn2 = *(const float4*)(xp + 32); xn3 = *(const float4*)(xp + 36);
      }
      // old-slot MLP1 for t+1
#pragma unroll
      for (int r = 0; r < 4; ++r) {
        const int s = (ph + 1 + r) % 5;
        nH = MFMA(w1h[2*r],   rb[s][0], nH);
        nH = MFMA(w1h[2*r+1], rb[s][1], nH);
        nL = MFMA(w1l[2*r],   rb[s][0], nL);
        nL = MFMA(w1l[2*r+1], rb[s][1], nL);
      }
      // x-stage: pack x[t+1] (loaded last step), XIN -> xin_s[(t+1)&1]
      bf16x8 th0, tl0, th1, tl1;
      pack_frag(xc0, xc1, th0, tl0);
      pack_frag(xc2, xc3, th1, tl1);
      bf16x8 f0b = (q15 & 2) ? tl0 : th0;
      bf16x8 f1b = (q15 & 2) ? tl1 : th1;
      f32x4 xH = vz, xL = vz;
      xH = MFMA(wxh[0], f0b, xH); xH = MFMA(wxh[1], f1b, xH);
      xL = MFMA(wxl[0], f0b, xL); xL = MFMA(wxl[1], f1b, xL);
      f32x4 xi = fold2(xH + xL) + biasv;
      if (q15 < 2) *(f32x4*)&xin_s[(t + 1) & 1][q15*64 + r0c] = xi;
      xc0 = xn0; xc1 = xn1; xc2 = xn2; xc3 = xn3;
    }
    aH = nH; aL = nL;
    barrier_fast();   // bar B: B1lds + xin_s staged
  };

  for (t5 = 0; t5 < TSTEPS; t5 += 5) {
    step(IC<0>{});
    step(IC<1>{});
    step(IC<2>{});
    step(IC<3>{});
    step(IC<4>{});
  }
}

extern "C" void kernel_launch(void* const* d_in, const int* in_sizes, int n_in,
                              void* d_out, int out_size, void* d_ws, size_t ws_size,
                              hipStream_t stream) {
  (void)in_sizes; (void)n_in; (void)out_size; (void)d_ws; (void)ws_size;
  const float* x    = (const float*)d_in[0];
  const float* h0   = (const float*)d_in[1];
  const float* W_in = (const float*)d_in[2];
  const float* b_in = (const float*)d_in[3];
  const float* W_hh = (const float*)d_in[4];
  const float* b_hh = (const float*)d_in[5];
  const float* W1   = (const float*)d_in[6];
  const float* b1   = (const float*)d_in[7];
  const float* W2   = (const float*)d_in[8];
  const float* b2   = (const float*)d_in[9];
  float* out = (float*)d_out;

  seq_kernel<<<NBLK, NTHR, 0, stream>>>(x, out, h0, W_in, b_in, W_hh, b_hh, W1, b1, W2, b2);
}